// Round 3
// baseline (1508.563 us; speedup 1.0000x reference)
//
#include <hip/hip_runtime.h>
#include <math.h>

// ---------------- problem constants ----------------
constexpr int Nn = 50000;
constexpr int Ee = 800000;
// output layout (f32 elements): [out_s N*64 | vec N*3 | node_feats_out N*256]
constexpr int VEC_OFF = Nn * 64;            // 3,200,000
constexpr int NF_OFF  = Nn * 67;            // 3,350,000

// ---------------- ws layout (bytes) — total exactly 51.2 MB ----------------
constexpr size_t AS_OFF = 0;                // f32 N*64   12.8 MB (atomic accum)
constexpr size_t AV_OFF = 12800000;         // f32 N*192  38.4 MB (atomic accum)

__device__ __forceinline__ float silu(float x) { return x / (1.f + __expf(-x)); }

// ================= K0: per-node up-projection =================
// up[n] stored INTERLEAVED as float4 per channel: up4[n*64 + k] =
// (s_up[k], vup0[k], vup1[k], vup2[k]) so k_edge gathers ONE dwordx4
// per edge per lane. Scratch target: node_feats_out region of out.
// Structure: c-outer loop, weights loaded once per c (not per node);
// node rows staged RAW in LDS, read via uniform broadcast (no scatter,
// no divergence, no int division).
__global__ __launch_bounds__(256) void k_up(
    const float* __restrict__ nfeat,
    const float* __restrict__ Wsu, const float* __restrict__ Wvu,
    float4* __restrict__ up4) {
    __shared__ float sR[4][8][256];       // raw node rows per wave

    const int tid = threadIdx.x, lane = tid & 63, w = tid >> 6;
    const int nb = blockIdx.x * 32 + w * 8;

    // stage 8 raw node rows (coalesced float4, linear — no transpose)
#pragma unroll
    for (int nn = 0; nn < 8; nn++) {
        int n = nb + nn;
        float4 nv = make_float4(0.f, 0.f, 0.f, 0.f);
        if (n < Nn) nv = *(const float4*)(nfeat + (size_t)n * 256 + lane * 4);
        *(float4*)(&sR[w][nn][lane * 4]) = nv;
    }
    // same-wave LDS write->read: in-order, no barrier needed

    float su[8], v0[8], v1[8], v2[8];
#pragma unroll
    for (int nn = 0; nn < 8; nn++) { su[nn]=0.f; v0[nn]=0.f; v1[nn]=0.f; v2[nn]=0.f; }

    for (int c = 0; c < 64; c++) {
        float u = Wsu[c * 64 + lane];      // lane = output channel
        float q = Wvu[c * 64 + lane];
#pragma unroll
        for (int nn = 0; nn < 8; nn++) {
            float sc = sR[w][nn][c];               // broadcast reads
            float a0 = sR[w][nn][64 + 3 * c + 0];  // v[c][i] raw layout
            float a1 = sR[w][nn][64 + 3 * c + 1];
            float a2 = sR[w][nn][64 + 3 * c + 2];
            su[nn] += sc * u;
            v0[nn] += a0 * q;
            v1[nn] += a1 * q;
            v2[nn] += a2 * q;
        }
    }
#pragma unroll
    for (int nn = 0; nn < 8; nn++) {
        int n = nb + nn;
        if (n < Nn)
            up4[(size_t)n * 64 + lane] = make_float4(su[nn], v0[nn], v1[nn], v2[nn]);
    }
}

// ================= K1: fused edge kernel (pure f32 VALU) =================
// Per block: 64 edges. Per wave: 16 edges (amortizes W1/W2 loads 2x vs 8).
//  1. h = silu(ef @ W1)            (lane = h channel)
//  2. issue gather batch0 (8 x dwordx4), then w = h @ W2 hides latency
//  3. issue gather batch1, message+scatter batch0, then batch1.
__global__ __launch_bounds__(256, 3) void k_edge(
    const float* __restrict__ vectors, const float* __restrict__ edge_feats,
    const int* __restrict__ snd_idx, const int* __restrict__ rcv_idx,
    const float4* __restrict__ up4,
    const float* __restrict__ W1, const float* __restrict__ W2,
    float* __restrict__ a_s, float* __restrict__ a_v) {
    __shared__ float sEf[64 * 64];
    __shared__ float sH[64 * 64];
    __shared__ float sY[64 * 3];
    __shared__ int sSnd[64], sRcv[64];

    const int tid = threadIdx.x;
    const int e0 = blockIdx.x * 64;

    {   // stage edge_feats tile f32 (coalesced float4, 16 floats/thread)
        int row = tid >> 2, cb = (tid & 3) * 16;
        const float4* src = (const float4*)(edge_feats + (size_t)(e0 + row) * 64 + cb);
        float4* dst = (float4*)(&sEf[row * 64 + cb]);
        dst[0] = src[0]; dst[1] = src[1]; dst[2] = src[2]; dst[3] = src[3];
    }
    if (tid < 64) {   // per-edge Y1 = sqrt(3)*rhat + indices
        int e = e0 + tid;
        float x = vectors[(size_t)e * 3 + 0];
        float y = vectors[(size_t)e * 3 + 1];
        float z = vectors[(size_t)e * 3 + 2];
        float n = sqrtf(x * x + y * y + z * z) + 1e-12f;
        float s = 1.7320508075688772f / n;
        sY[tid * 3 + 0] = x * s; sY[tid * 3 + 1] = y * s; sY[tid * 3 + 2] = z * s;
        sSnd[tid] = snd_idx[e];
        sRcv[tid] = rcv_idx[e];
    }
    __syncthreads();

    const int lane = tid & 63, w = tid >> 6, m0 = w * 16;

    // ---- h = silu(ef @ W1) ----
    {
        float hacc[16];
#pragma unroll
        for (int e = 0; e < 16; e++) hacc[e] = 0.f;
        for (int c = 0; c < 64; c += 4) {
            float w0 = W1[(c + 0) * 64 + lane], w1 = W1[(c + 1) * 64 + lane],
                  w2 = W1[(c + 2) * 64 + lane], w3 = W1[(c + 3) * 64 + lane];
#pragma unroll
            for (int e = 0; e < 16; e++) {
                const float4 ef = *(const float4*)(&sEf[(m0 + e) * 64 + c]);
                hacc[e] += ef.x * w0 + ef.y * w1 + ef.z * w2 + ef.w * w3;
            }
        }
#pragma unroll
        for (int e = 0; e < 16; e++) sH[(m0 + e) * 64 + lane] = silu(hacc[e]);
        // sH rows are wave-private: same-wave write->read, no barrier needed
    }

    // ---- issue gather batch0 early: mlp2 hides its latency ----
    float4 g0[8];
#pragma unroll
    for (int e = 0; e < 8; e++)
        g0[e] = up4[(size_t)sSnd[m0 + e] * 64 + lane];

    // ---- w = h @ W2 : wacc[q][e] = w[e][q*64 + lane] ----
    float wacc[5][16];
#pragma unroll
    for (int q = 0; q < 5; q++)
#pragma unroll
        for (int e = 0; e < 16; e++) wacc[q][e] = 0.f;
#pragma unroll 2
    for (int c = 0; c < 64; c++) {
        float wq0 = W2[c * 320 + 0 * 64 + lane];
        float wq1 = W2[c * 320 + 1 * 64 + lane];
        float wq2 = W2[c * 320 + 2 * 64 + lane];
        float wq3 = W2[c * 320 + 3 * 64 + lane];
        float wq4 = W2[c * 320 + 4 * 64 + lane];
#pragma unroll
        for (int e = 0; e < 16; e++) {
            float hb = sH[(m0 + e) * 64 + c];
            wacc[0][e] += hb * wq0; wacc[1][e] += hb * wq1; wacc[2][e] += hb * wq2;
            wacc[3][e] += hb * wq3; wacc[4][e] += hb * wq4;
        }
    }

    // ---- issue gather batch1, then message batch0 (hides b1 latency) ----
    float4 g1[8];
#pragma unroll
    for (int e = 0; e < 8; e++)
        g1[e] = up4[(size_t)sSnd[m0 + 8 + e] * 64 + lane];

#pragma unroll
    for (int b = 0; b < 2; b++) {
#pragma unroll
        for (int e8 = 0; e8 < 8; e8++) {
            const int e = b * 8 + e8;
            const float4 g = (b == 0) ? g0[e8] : g1[e8];
            const int rcv = sRcv[m0 + e];
            const float Y0 = sY[(m0 + e) * 3 + 0];
            const float Y1 = sY[(m0 + e) * 3 + 1];
            const float Y2 = sY[(m0 + e) * 3 + 2];
            const float sj = g.x, vj0 = g.y, vj1 = g.z, vj2 = g.w;
            const float w0 = wacc[0][e], w1 = wacc[1][e], w2 = wacc[2][e],
                        w3 = wacc[3][e], w4 = wacc[4][e];
            float vdY = vj0 * Y0 + vj1 * Y1 + vj2 * Y2;
            float ms = w0 * sj + w1 * vdY;
            float cx = vj1 * Y2 - vj2 * Y1;
            float cy = vj2 * Y0 - vj0 * Y2;
            float cz = vj0 * Y1 - vj1 * Y0;
            float t = w2 * sj;
            atomicAdd(a_s + (size_t)rcv * 64 + lane, ms);
            float* avp = a_v + (size_t)rcv * 192;
            atomicAdd(avp + lane,       t * Y0 + w3 * vj0 + w4 * cx);
            atomicAdd(avp + 64 + lane,  t * Y1 + w3 * vj1 + w4 * cy);
            atomicAdd(avp + 128 + lane, t * Y2 + w3 * vj2 + w4 * cz);
        }
    }
}

// ================= K2: node post (pure f32 VALU) =================
// Block 256 = 4 waves; each wave owns 8 nodes. pv kept in REGISTERS to
// the end (vec reduction is per-lane-channel) -> Y holds ps only.
// LDS 64KB -> 40KB: 4 blocks/CU instead of 2.
__global__ __launch_bounds__(256) void k_post(
    const float* __restrict__ a_s, const float* __restrict__ a_v,
    const float* __restrict__ Wsp, const float* __restrict__ Wvp,
    const float* __restrict__ Ps1, const float* __restrict__ Ps2,
    const float* __restrict__ Ps3, const float* __restrict__ Pvv,
    const float* __restrict__ Pv1, const float* __restrict__ Pv2,
    const float* __restrict__ Pv3,
    const float* __restrict__ Rw1, const float* __restrict__ Rw2,
    const float* __restrict__ Rgate, const float* __restrict__ Rvmix,
    float* __restrict__ out) {
    __shared__ float Xb[4][8 * 256];   // a/16 -> (as2|av2) -> hr in s-section
    __shared__ float Yb[4][8 * 64];    // ps only

    const int tid = threadIdx.x, lane = tid & 63, w = tid >> 6;
    const int nb = blockIdx.x * 32 + w * 8;   // first node of this wave
    float* X = &Xb[w][0];
    float* Y = &Yb[w][0];

    // ---- stage a_s/a_v (x 1/16) ----
#pragma unroll
    for (int nn = 0; nn < 8; nn++) {
        int n = nb + nn;
        if (n < Nn) {
            X[nn * 256 + lane]       = a_s[(size_t)n * 64 + lane] * 0.0625f;
            X[nn * 256 + 64 + lane]  = a_v[(size_t)n * 192 + lane] * 0.0625f;
            X[nn * 256 + 128 + lane] = a_v[(size_t)n * 192 + 64 + lane] * 0.0625f;
            X[nn * 256 + 192 + lane] = a_v[(size_t)n * 192 + 128 + lane] * 0.0625f;
        } else {
            X[nn * 256 + lane] = 0.f; X[nn * 256 + 64 + lane] = 0.f;
            X[nn * 256 + 128 + lane] = 0.f; X[nn * 256 + 192 + lane] = 0.f;
        }
    }

    // ---- phase A: as2 = a_s@Wsp ; av2_i = a_v_i@Wvp (lane = out channel) ----
    {
        float as2[8], ava[8], avb[8], avc[8];
#pragma unroll
        for (int nn = 0; nn < 8; nn++) { as2[nn]=0.f; ava[nn]=0.f; avb[nn]=0.f; avc[nn]=0.f; }
        for (int c = 0; c < 64; c++) {
            float wsp = Wsp[c * 64 + lane];
            float wvp = Wvp[c * 64 + lane];
#pragma unroll
            for (int nn = 0; nn < 8; nn++) {
                as2[nn] += X[nn * 256 + c] * wsp;
                ava[nn] += X[nn * 256 + 64 + c] * wvp;
                avb[nn] += X[nn * 256 + 128 + c] * wvp;
                avc[nn] += X[nn * 256 + 192 + c] * wvp;
            }
        }
#pragma unroll
        for (int nn = 0; nn < 8; nn++) {   // in-place (all reads done)
            X[nn * 256 + lane] = as2[nn];
            X[nn * 256 + 64 + lane] = ava[nn];
            X[nn * 256 + 128 + lane] = avb[nn];
            X[nn * 256 + 192 + lane] = avc[nn];
        }
    }

    // ---- phase B: ps (-> Y + out), pv kept in regs ----
    float pv0[8], pv1[8], pv2[8];
    {
        float ps[8];
#pragma unroll
        for (int nn = 0; nn < 8; nn++) { ps[nn]=0.f; pv0[nn]=0.f; pv1[nn]=0.f; pv2[nn]=0.f; }
        for (int c = 0; c < 64; c++) {
            float p1 = Ps1[c * 64 + lane], p2 = Ps2[c * 64 + lane],
                  p3 = Ps3[c * 64 + lane], pv = Pvv[c * 64 + lane];
            float q1 = Pv1[c * 64 + lane], q2 = Pv2[c * 64 + lane],
                  q3 = Pv3[c * 64 + lane];
#pragma unroll
            for (int nn = 0; nn < 8; nn++) {
                float a  = X[nn * 256 + c];
                float b0 = X[nn * 256 + 64 + c];
                float b1 = X[nn * 256 + 128 + c];
                float b2 = X[nn * 256 + 192 + c];
                float a2 = a * a, a3 = a2 * a;
                float vv = b0 * b0 + b1 * b1 + b2 * b2;
                ps[nn] += a * p1 + a2 * p2 + a3 * p3 + vv * pv;
                float qq = q1 + a * q2 + a2 * q3;
                pv0[nn] += b0 * qq; pv1[nn] += b1 * qq; pv2[nn] += b2 * qq;
            }
        }
#pragma unroll
        for (int nn = 0; nn < 8; nn++) {
            Y[nn * 64 + lane] = ps[nn];
            int n = nb + nn;
            if (n < Nn) {   // node_feats_out = [ps | pv (k*3+i)]
                float* nf = out + NF_OFF + (size_t)n * 256;
                nf[lane] = ps[nn];
                nf[64 + lane * 3 + 0] = pv0[nn];
                nf[64 + lane * 3 + 1] = pv1[nn];
                nf[64 + lane * 3 + 2] = pv2[nn];
            }
        }
    }

    // ---- phase C: hr = silu(ps @ Rw1) -> X s-section (dead) ----
    {
        float hr[8];
#pragma unroll
        for (int nn = 0; nn < 8; nn++) hr[nn] = 0.f;
        for (int c = 0; c < 64; c++) {
            float r1 = Rw1[c * 64 + lane];
#pragma unroll
            for (int nn = 0; nn < 8; nn++) hr[nn] += Y[nn * 64 + c] * r1;
        }
#pragma unroll
        for (int nn = 0; nn < 8; nn++) X[nn * 256 + lane] = silu(hr[nn]);
    }

    // ---- gate = silu(hr @ Rgate) : per-node wave reduction ----
    float gate[8];
    {
        float rg = Rgate[lane];
#pragma unroll
        for (int nn = 0; nn < 8; nn++) {
            float p = X[nn * 256 + lane] * rg;
            p += __shfl_xor(p, 1);  p += __shfl_xor(p, 2);
            p += __shfl_xor(p, 4);  p += __shfl_xor(p, 8);
            p += __shfl_xor(p, 16); p += __shfl_xor(p, 32);
            gate[nn] = silu(p);
        }
    }

    // ---- out_s = hr @ Rw2 ----
    {
        float os[8];
#pragma unroll
        for (int nn = 0; nn < 8; nn++) os[nn] = 0.f;
        for (int c = 0; c < 64; c++) {
            float r2 = Rw2[c * 64 + lane];
#pragma unroll
            for (int nn = 0; nn < 8; nn++) os[nn] += X[nn * 256 + c] * r2;
        }
#pragma unroll
        for (int nn = 0; nn < 8; nn++) {
            int n = nb + nn;
            if (n < Nn) out[(size_t)n * 64 + lane] = os[nn];
        }
    }

    // ---- vec = (sum_k pv_i[k]*Rvmix[k]) * gate  (pv straight from regs) ----
    {
        float vm = Rvmix[lane];
#pragma unroll
        for (int nn = 0; nn < 8; nn++) {
            int n = nb + nn;
#pragma unroll
            for (int j = 0; j < 3; j++) {
                float p = ((j == 0) ? pv0[nn] : (j == 1) ? pv1[nn] : pv2[nn]) * vm;
                p += __shfl_xor(p, 1);  p += __shfl_xor(p, 2);
                p += __shfl_xor(p, 4);  p += __shfl_xor(p, 8);
                p += __shfl_xor(p, 16); p += __shfl_xor(p, 32);
                if (lane == j && n < Nn)
                    out[VEC_OFF + (size_t)n * 3 + j] = p * gate[nn];
            }
        }
    }
}

// ---------------- host ----------------
extern "C" void kernel_launch(void* const* d_in, const int* in_sizes, int n_in,
                              void* d_out, int out_size, void* d_ws, size_t ws_size,
                              hipStream_t stream) {
    (void)in_sizes; (void)n_in; (void)out_size; (void)ws_size;
    const float* vectors    = (const float*)d_in[0];
    const float* node_feats = (const float*)d_in[2];
    const float* edge_feats = (const float*)d_in[3];
    const int*   edge_index = (const int*)d_in[4];
    const float* W_s_up   = (const float*)d_in[5];
    const float* W_v_up   = (const float*)d_in[6];
    const float* mlp_w1   = (const float*)d_in[7];
    const float* mlp_w2   = (const float*)d_in[8];
    const float* W_s_post = (const float*)d_in[9];
    const float* W_v_post = (const float*)d_in[10];
    const float* P_s1 = (const float*)d_in[11];
    const float* P_s2 = (const float*)d_in[12];
    const float* P_s3 = (const float*)d_in[13];
    const float* P_vv = (const float*)d_in[14];
    const float* P_v1 = (const float*)d_in[15];
    const float* P_v2 = (const float*)d_in[16];
    const float* P_v3 = (const float*)d_in[17];
    const float* R_w1 = (const float*)d_in[18];
    const float* R_w2 = (const float*)d_in[19];
    const float* R_gate = (const float*)d_in[20];
    const float* R_vmix = (const float*)d_in[21];

    char* ws = (char*)d_ws;
    float* a_s = (float*)(ws + AS_OFF);
    float* a_v = (float*)(ws + AV_OFF);
    float* outp = (float*)d_out;
    // scratch for per-node up-projection: node_feats_out region of the
    // output buffer (N*256 f32 = 51.2 MB), interleaved float4 per channel.
    float4* up4 = (float4*)(outp + NF_OFF);

    // zero segment-sum accumulators (51.2 MB)
    hipMemsetAsync(ws, 0, 51200000, stream);

    k_up<<<(Nn + 31) / 32, 256, 0, stream>>>(node_feats, W_s_up, W_v_up, up4);

    k_edge<<<Ee / 64, 256, 0, stream>>>(vectors, edge_feats,
                                        edge_index, edge_index + Ee,
                                        up4, mlp_w1, mlp_w2, a_s, a_v);

    k_post<<<(Nn + 31) / 32, 256, 0, stream>>>(a_s, a_v,
                                               W_s_post, W_v_post,
                                               P_s1, P_s2, P_s3, P_vv,
                                               P_v1, P_v2, P_v3,
                                               R_w1, R_w2, R_gate, R_vmix,
                                               outp);
}

// Round 4
// 1344.844 us; speedup vs baseline: 1.1217x; 1.1217x over previous
//
#include <hip/hip_runtime.h>
#include <math.h>

// ---------------- problem constants ----------------
constexpr int Nn = 50000;
constexpr int Ee = 800000;
// output layout (f32 elements): [out_s N*64 | vec N*3 | node_feats_out N*256]
constexpr int VEC_OFF = Nn * 64;            // 3,200,000
constexpr int NF_OFF  = Nn * 67;            // 3,350,000

// ---------------- ws layout (bytes) — total exactly 51.2 MB ----------------
constexpr size_t AS_OFF = 0;                // f32 N*64   12.8 MB (atomic accum)
constexpr size_t AV_OFF = 12800000;         // f32 N*192  38.4 MB (atomic accum)

__device__ __forceinline__ float silu(float x) { return x / (1.f + __expf(-x)); }

// ================= K0: per-node up-projection =================
// up[n] stored INTERLEAVED as float4 per channel: up4[n*64 + k] =
// (s_up[k], vup0[k], vup1[k], vup2[k]) so k_edge gathers ONE dwordx4
// per edge per lane. Scratch target: node_feats_out region of out.
// c-outer loop: weights loaded once per c; node rows staged RAW in LDS,
// read via uniform broadcast (no scatter, no divergence, no int division).
__global__ __launch_bounds__(256) void k_up(
    const float* __restrict__ nfeat,
    const float* __restrict__ Wsu, const float* __restrict__ Wvu,
    float4* __restrict__ up4) {
    __shared__ float sR[4][8][256];       // raw node rows per wave

    const int tid = threadIdx.x, lane = tid & 63, w = tid >> 6;
    const int nb = blockIdx.x * 32 + w * 8;

    // stage 8 raw node rows (coalesced float4, linear — no transpose)
#pragma unroll
    for (int nn = 0; nn < 8; nn++) {
        int n = nb + nn;
        float4 nv = make_float4(0.f, 0.f, 0.f, 0.f);
        if (n < Nn) nv = *(const float4*)(nfeat + (size_t)n * 256 + lane * 4);
        *(float4*)(&sR[w][nn][lane * 4]) = nv;
    }
    // same-wave LDS write->read: in-order, no barrier needed

    float su[8], v0[8], v1[8], v2[8];
#pragma unroll
    for (int nn = 0; nn < 8; nn++) { su[nn]=0.f; v0[nn]=0.f; v1[nn]=0.f; v2[nn]=0.f; }

    for (int c = 0; c < 64; c++) {
        float u = Wsu[c * 64 + lane];      // lane = output channel
        float q = Wvu[c * 64 + lane];
#pragma unroll
        for (int nn = 0; nn < 8; nn++) {
            float sc = sR[w][nn][c];               // broadcast reads
            float a0 = sR[w][nn][64 + 3 * c + 0];  // v[c][i] raw layout
            float a1 = sR[w][nn][64 + 3 * c + 1];
            float a2 = sR[w][nn][64 + 3 * c + 2];
            su[nn] += sc * u;
            v0[nn] += a0 * q;
            v1[nn] += a1 * q;
            v2[nn] += a2 * q;
        }
    }
#pragma unroll
    for (int nn = 0; nn < 8; nn++) {
        int n = nb + nn;
        if (n < Nn)
            up4[(size_t)n * 64 + lane] = make_float4(su[nn], v0[nn], v1[nn], v2[nn]);
    }
}

// ================= K1: fused edge kernel (pure f32 VALU) =================
// Round-1 winning structure (8 edges/wave, 32/block, VGPR ~52) plus:
//  (a) conflict-free FLAT sEf staging (tile is contiguous in global),
//  (b) single dwordx4 gather per edge from interleaved up4.
__global__ __launch_bounds__(256, 3) void k_edge(
    const float* __restrict__ vectors, const float* __restrict__ edge_feats,
    const int* __restrict__ snd_idx, const int* __restrict__ rcv_idx,
    const float4* __restrict__ up4,
    const float* __restrict__ W1, const float* __restrict__ W2,
    float* __restrict__ a_s, float* __restrict__ a_v) {
    __shared__ float sEf[32 * 64];
    __shared__ float sH[32 * 64];
    __shared__ float sY[32 * 3];
    __shared__ int sSnd[32], sRcv[32];

    const int tid = threadIdx.x;
    const int e0 = blockIdx.x * 32;

    {   // stage edge_feats tile FLAT: 2048 contiguous f32 = 512 float4.
        // lane l's b128 write -> banks 4l..4l+3 (mod 32): minimum aliasing,
        // zero excess conflicts. Global side fully coalesced.
        const float4* src = (const float4*)(edge_feats + (size_t)e0 * 64);
        float4* dst = (float4*)sEf;
        dst[tid] = src[tid];
        dst[tid + 256] = src[tid + 256];
    }
    if (tid < 32) {   // per-edge Y1 = sqrt(3)*rhat + indices
        int e = e0 + tid;
        float x = vectors[(size_t)e * 3 + 0];
        float y = vectors[(size_t)e * 3 + 1];
        float z = vectors[(size_t)e * 3 + 2];
        float n = sqrtf(x * x + y * y + z * z) + 1e-12f;
        float s = 1.7320508075688772f / n;
        sY[tid * 3 + 0] = x * s; sY[tid * 3 + 1] = y * s; sY[tid * 3 + 2] = z * s;
        sSnd[tid] = snd_idx[e];
        sRcv[tid] = rcv_idx[e];
    }
    __syncthreads();

    const int lane = tid & 63, w = tid >> 6, m0 = w * 8;

    // ---- h = silu(ef @ W1) ----
    {
        float hacc[8];
#pragma unroll
        for (int e = 0; e < 8; e++) hacc[e] = 0.f;
        for (int c = 0; c < 64; c += 4) {
            float w0 = W1[(c + 0) * 64 + lane], w1 = W1[(c + 1) * 64 + lane],
                  w2 = W1[(c + 2) * 64 + lane], w3 = W1[(c + 3) * 64 + lane];
#pragma unroll
            for (int e = 0; e < 8; e++) {
                const float4 ef = *(const float4*)(&sEf[(m0 + e) * 64 + c]);
                hacc[e] += ef.x * w0 + ef.y * w1 + ef.z * w2 + ef.w * w3;
            }
        }
#pragma unroll
        for (int e = 0; e < 8; e++) sH[(m0 + e) * 64 + lane] = silu(hacc[e]);
        // sH rows are wave-private: same-wave write->read, no barrier needed
    }

    // ---- w = h @ W2 : wacc[q][e] = w[e][q*64 + lane] ----
    float wacc[5][8];
#pragma unroll
    for (int q = 0; q < 5; q++)
#pragma unroll
        for (int e = 0; e < 8; e++) wacc[q][e] = 0.f;
#pragma unroll 2
    for (int c = 0; c < 64; c++) {
        float wq0 = W2[c * 320 + 0 * 64 + lane];
        float wq1 = W2[c * 320 + 1 * 64 + lane];
        float wq2 = W2[c * 320 + 2 * 64 + lane];
        float wq3 = W2[c * 320 + 3 * 64 + lane];
        float wq4 = W2[c * 320 + 4 * 64 + lane];
#pragma unroll
        for (int e = 0; e < 8; e++) {
            float hb = sH[(m0 + e) * 64 + c];
            wacc[0][e] += hb * wq0; wacc[1][e] += hb * wq1; wacc[2][e] += hb * wq2;
            wacc[3][e] += hb * wq3; wacc[4][e] += hb * wq4;
        }
    }

    // ---- gather pre-projected rows: one dwordx4 per edge, all issued ----
    float4 g[8];
#pragma unroll
    for (int e = 0; e < 8; e++)
        g[e] = up4[(size_t)sSnd[m0 + e] * 64 + lane];

    // ---- message compute + scatter ----
#pragma unroll
    for (int e = 0; e < 8; e++) {
        const int rcv = sRcv[m0 + e];
        const float Y0 = sY[(m0 + e) * 3 + 0];
        const float Y1 = sY[(m0 + e) * 3 + 1];
        const float Y2 = sY[(m0 + e) * 3 + 2];
        const float sj = g[e].x, vj0 = g[e].y, vj1 = g[e].z, vj2 = g[e].w;
        const float w0 = wacc[0][e], w1 = wacc[1][e], w2 = wacc[2][e],
                    w3 = wacc[3][e], w4 = wacc[4][e];
        float vdY = vj0 * Y0 + vj1 * Y1 + vj2 * Y2;
        float ms = w0 * sj + w1 * vdY;
        float cx = vj1 * Y2 - vj2 * Y1;
        float cy = vj2 * Y0 - vj0 * Y2;
        float cz = vj0 * Y1 - vj1 * Y0;
        float t = w2 * sj;
        atomicAdd(a_s + (size_t)rcv * 64 + lane, ms);
        float* avp = a_v + (size_t)rcv * 192;
        atomicAdd(avp + lane,       t * Y0 + w3 * vj0 + w4 * cx);
        atomicAdd(avp + 64 + lane,  t * Y1 + w3 * vj1 + w4 * cy);
        atomicAdd(avp + 128 + lane, t * Y2 + w3 * vj2 + w4 * cz);
    }
}

// ================= K2: node post (round-1 version, known-good cost) =================
// Block 256 = 4 waves; each wave owns 8 nodes. All weights read from
// global (L1/L2-hot, coalesced: lane = output channel). Per-wave LDS
// X/Y buffers; wave-private -> no barriers needed after staging.
__global__ __launch_bounds__(256) void k_post(
    const float* __restrict__ a_s, const float* __restrict__ a_v,
    const float* __restrict__ Wsp, const float* __restrict__ Wvp,
    const float* __restrict__ Ps1, const float* __restrict__ Ps2,
    const float* __restrict__ Ps3, const float* __restrict__ Pvv,
    const float* __restrict__ Pv1, const float* __restrict__ Pv2,
    const float* __restrict__ Pv3,
    const float* __restrict__ Rw1, const float* __restrict__ Rw2,
    const float* __restrict__ Rgate, const float* __restrict__ Rvmix,
    float* __restrict__ out) {
    __shared__ float Xb[4][8 * 256];   // a/16 -> (as2|av2) -> hr in s-section
    __shared__ float Yb[4][8 * 256];   // ps|pv0|pv1|pv2

    const int tid = threadIdx.x, lane = tid & 63, w = tid >> 6;
    const int nb = blockIdx.x * 32 + w * 8;   // first node of this wave
    float* X = &Xb[w][0];
    float* Y = &Yb[w][0];

    // ---- stage a_s/a_v (x 1/16) ----
#pragma unroll
    for (int nn = 0; nn < 8; nn++) {
        int n = nb + nn;
        if (n < Nn) {
            X[nn * 256 + lane]       = a_s[(size_t)n * 64 + lane] * 0.0625f;
            X[nn * 256 + 64 + lane]  = a_v[(size_t)n * 192 + lane] * 0.0625f;
            X[nn * 256 + 128 + lane] = a_v[(size_t)n * 192 + 64 + lane] * 0.0625f;
            X[nn * 256 + 192 + lane] = a_v[(size_t)n * 192 + 128 + lane] * 0.0625f;
        } else {
            X[nn * 256 + lane] = 0.f; X[nn * 256 + 64 + lane] = 0.f;
            X[nn * 256 + 128 + lane] = 0.f; X[nn * 256 + 192 + lane] = 0.f;
        }
    }

    // ---- phase A: as2 = a_s@Wsp ; av2_i = a_v_i@Wvp (lane = out channel) ----
    {
        float as2[8], ava[8], avb[8], avc[8];
#pragma unroll
        for (int nn = 0; nn < 8; nn++) { as2[nn]=0.f; ava[nn]=0.f; avb[nn]=0.f; avc[nn]=0.f; }
        for (int c = 0; c < 64; c++) {
            float wsp = Wsp[c * 64 + lane];
            float wvp = Wvp[c * 64 + lane];
#pragma unroll
            for (int nn = 0; nn < 8; nn++) {
                as2[nn] += X[nn * 256 + c] * wsp;
                ava[nn] += X[nn * 256 + 64 + c] * wvp;
                avb[nn] += X[nn * 256 + 128 + c] * wvp;
                avc[nn] += X[nn * 256 + 192 + c] * wvp;
            }
        }
#pragma unroll
        for (int nn = 0; nn < 8; nn++) {   // in-place (all reads done)
            X[nn * 256 + lane] = as2[nn];
            X[nn * 256 + 64 + lane] = ava[nn];
            X[nn * 256 + 128 + lane] = avb[nn];
            X[nn * 256 + 192 + lane] = avc[nn];
        }
    }

    // ---- phase B: ps, pv ----
    {
        float ps[8], pv0[8], pv1[8], pv2[8];
#pragma unroll
        for (int nn = 0; nn < 8; nn++) { ps[nn]=0.f; pv0[nn]=0.f; pv1[nn]=0.f; pv2[nn]=0.f; }
        for (int c = 0; c < 64; c++) {
            float p1 = Ps1[c * 64 + lane], p2 = Ps2[c * 64 + lane],
                  p3 = Ps3[c * 64 + lane], pv = Pvv[c * 64 + lane];
            float q1 = Pv1[c * 64 + lane], q2 = Pv2[c * 64 + lane],
                  q3 = Pv3[c * 64 + lane];
#pragma unroll
            for (int nn = 0; nn < 8; nn++) {
                float a  = X[nn * 256 + c];
                float b0 = X[nn * 256 + 64 + c];
                float b1 = X[nn * 256 + 128 + c];
                float b2 = X[nn * 256 + 192 + c];
                float a2 = a * a, a3 = a2 * a;
                float vv = b0 * b0 + b1 * b1 + b2 * b2;
                ps[nn] += a * p1 + a2 * p2 + a3 * p3 + vv * pv;
                float qq = q1 + a * q2 + a2 * q3;
                pv0[nn] += b0 * qq; pv1[nn] += b1 * qq; pv2[nn] += b2 * qq;
            }
        }
#pragma unroll
        for (int nn = 0; nn < 8; nn++) {
            Y[nn * 256 + lane] = ps[nn];
            Y[nn * 256 + 64 + lane] = pv0[nn];
            Y[nn * 256 + 128 + lane] = pv1[nn];
            Y[nn * 256 + 192 + lane] = pv2[nn];
            int n = nb + nn;
            if (n < Nn) {   // node_feats_out = [ps | pv (k*3+i)]
                float* nf = out + NF_OFF + (size_t)n * 256;
                nf[lane] = ps[nn];
                nf[64 + lane * 3 + 0] = pv0[nn];
                nf[64 + lane * 3 + 1] = pv1[nn];
                nf[64 + lane * 3 + 2] = pv2[nn];
            }
        }
    }

    // ---- phase C: hr = silu(ps @ Rw1) -> X s-section (dead) ----
    {
        float hr[8];
#pragma unroll
        for (int nn = 0; nn < 8; nn++) hr[nn] = 0.f;
        for (int c = 0; c < 64; c++) {
            float r1 = Rw1[c * 64 + lane];
#pragma unroll
            for (int nn = 0; nn < 8; nn++) hr[nn] += Y[nn * 256 + c] * r1;
        }
#pragma unroll
        for (int nn = 0; nn < 8; nn++) X[nn * 256 + lane] = silu(hr[nn]);
    }

    // ---- gate = silu(hr @ Rgate) : per-node wave reduction ----
    float gate[8];
    {
        float rg = Rgate[lane];
#pragma unroll
        for (int nn = 0; nn < 8; nn++) {
            float p = X[nn * 256 + lane] * rg;
            p += __shfl_xor(p, 1);  p += __shfl_xor(p, 2);
            p += __shfl_xor(p, 4);  p += __shfl_xor(p, 8);
            p += __shfl_xor(p, 16); p += __shfl_xor(p, 32);
            gate[nn] = silu(p);
        }
    }

    // ---- out_s = hr @ Rw2 ----
    {
        float os[8];
#pragma unroll
        for (int nn = 0; nn < 8; nn++) os[nn] = 0.f;
        for (int c = 0; c < 64; c++) {
            float r2 = Rw2[c * 64 + lane];
#pragma unroll
            for (int nn = 0; nn < 8; nn++) os[nn] += X[nn * 256 + c] * r2;
        }
#pragma unroll
        for (int nn = 0; nn < 8; nn++) {
            int n = nb + nn;
            if (n < Nn) out[(size_t)n * 64 + lane] = os[nn];
        }
    }

    // ---- vec = (sum_k pv_i[k]*Rvmix[k]) * gate ----
    {
        float vm = Rvmix[lane];
#pragma unroll
        for (int nn = 0; nn < 8; nn++) {
            int n = nb + nn;
#pragma unroll
            for (int j = 0; j < 3; j++) {
                float p = Y[nn * 256 + 64 + j * 64 + lane] * vm;
                p += __shfl_xor(p, 1);  p += __shfl_xor(p, 2);
                p += __shfl_xor(p, 4);  p += __shfl_xor(p, 8);
                p += __shfl_xor(p, 16); p += __shfl_xor(p, 32);
                if (lane == j && n < Nn)
                    out[VEC_OFF + (size_t)n * 3 + j] = p * gate[nn];
            }
        }
    }
}

// ---------------- host ----------------
extern "C" void kernel_launch(void* const* d_in, const int* in_sizes, int n_in,
                              void* d_out, int out_size, void* d_ws, size_t ws_size,
                              hipStream_t stream) {
    (void)in_sizes; (void)n_in; (void)out_size; (void)ws_size;
    const float* vectors    = (const float*)d_in[0];
    const float* node_feats = (const float*)d_in[2];
    const float* edge_feats = (const float*)d_in[3];
    const int*   edge_index = (const int*)d_in[4];
    const float* W_s_up   = (const float*)d_in[5];
    const float* W_v_up   = (const float*)d_in[6];
    const float* mlp_w1   = (const float*)d_in[7];
    const float* mlp_w2   = (const float*)d_in[8];
    const float* W_s_post = (const float*)d_in[9];
    const float* W_v_post = (const float*)d_in[10];
    const float* P_s1 = (const float*)d_in[11];
    const float* P_s2 = (const float*)d_in[12];
    const float* P_s3 = (const float*)d_in[13];
    const float* P_vv = (const float*)d_in[14];
    const float* P_v1 = (const float*)d_in[15];
    const float* P_v2 = (const float*)d_in[16];
    const float* P_v3 = (const float*)d_in[17];
    const float* R_w1 = (const float*)d_in[18];
    const float* R_w2 = (const float*)d_in[19];
    const float* R_gate = (const float*)d_in[20];
    const float* R_vmix = (const float*)d_in[21];

    char* ws = (char*)d_ws;
    float* a_s = (float*)(ws + AS_OFF);
    float* a_v = (float*)(ws + AV_OFF);
    float* outp = (float*)d_out;
    // scratch for per-node up-projection: node_feats_out region of the
    // output buffer (N*256 f32 = 51.2 MB), interleaved float4 per channel.
    float4* up4 = (float4*)(outp + NF_OFF);

    // zero segment-sum accumulators (51.2 MB)
    hipMemsetAsync(ws, 0, 51200000, stream);

    k_up<<<(Nn + 31) / 32, 256, 0, stream>>>(node_feats, W_s_up, W_v_up, up4);

    k_edge<<<Ee / 32, 256, 0, stream>>>(vectors, edge_feats,
                                        edge_index, edge_index + Ee,
                                        up4, mlp_w1, mlp_w2, a_s, a_v);

    k_post<<<(Nn + 31) / 32, 256, 0, stream>>>(a_s, a_v,
                                               W_s_post, W_v_post,
                                               P_s1, P_s2, P_s3, P_vv,
                                               P_v1, P_v2, P_v3,
                                               R_w1, R_w2, R_gate, R_vmix,
                                               outp);
}